// Round 4
// baseline (47.200 us; speedup 1.0000x reference)
//
#include <hip/hip_runtime.h>

#define W 256
#define HTOT 1280            // num_img * H = 5 * 256
#define RR 16                // output rows per wave (stripe height)
#define SPB (HTOT / RR)      // 80 stripes per batch
#define BS 64                // batch size
#define WPB 2                // waves per block
#define NC (SPB * 3)         // 240 candidates per batch
#define NEG_FILL -1e9f

struct Cand { float v; int i; };

__device__ __forceinline__ bool better(float av, int ai, float bv, int bi) {
    // larger value wins; tie -> smaller flat index (XLA top_k tie-break)
    return (av > bv) || (av == bv && ai < bi);
}

__device__ __forceinline__ void merge3(float cv, int ci,
                                       float& v0, int& i0,
                                       float& v1, int& i1,
                                       float& v2, int& i2) {
    if (better(cv, ci, v2, i2)) {
        if (better(cv, ci, v1, i1)) {
            v2 = v1; i2 = i1;
            if (better(cv, ci, v0, i0)) { v1 = v0; i1 = i0; v0 = cv; i0 = ci; }
            else { v1 = cv; i1 = ci; }
        } else { v2 = cv; i2 = ci; }
    }
}

// 2 independent 64-lane waves per block; each wave owns one 16-row stripe.
// No LDS, no __syncthreads. Thread owns 4 columns; halo via shfl;
// 4-row software pipeline of float4 loads.
__global__ __launch_bounds__(64 * WPB) void peaks_phase1(const float* __restrict__ hm,
                                                         Cand* __restrict__ ws) {
    const int lane = threadIdx.x & 63;
    const int wv   = threadIdx.x >> 6;
    const int g = blockIdx.x * WPB + wv;   // 0..5119 global stripe id
    const int b = g / SPB;                 // batch (wave-uniform)
    const int s = g - b * SPB;             // stripe
    const int r0 = s * RR;
    const float NINF = -__builtin_inff();

    const float* base = hm + (size_t)b * (size_t)(HTOT * W) + lane * 4;

    auto LOADROW = [&](int gr) -> float4 {
        float4 v;
        if ((unsigned)gr < (unsigned)HTOT) {
            v = *(const float4*)(base + (size_t)gr * W);
        } else {
            v.x = NINF; v.y = NINF; v.z = NINF; v.w = NINF;
        }
        return v;
    };

    // vertical chains: h[k][j] = horizontal 5-max of row (cur-4+k), col j
    float h[5][4];
    float raw0[4], raw1[4], raw2[4];
    #pragma unroll
    for (int k = 0; k < 5; ++k) {
        h[k][0] = NINF; h[k][1] = NINF; h[k][2] = NINF; h[k][3] = NINF;
    }
    #pragma unroll
    for (int j = 0; j < 4; ++j) { raw0[j] = NINF; raw1[j] = NINF; raw2[j] = NINF; }

    float v0 = NINF, v1 = NINF, v2 = NINF;
    int   i0 = 0x7fffffff, i1 = 0x7fffffff, i2 = 0x7fffffff;

    // software pipeline: 4 rows in flight
    float4 p0 = LOADROW(r0 - 2);
    float4 p1 = LOADROW(r0 - 1);
    float4 p2 = LOADROW(r0);
    float4 p3 = LOADROW(r0 + 1);

    #pragma unroll
    for (int r = 0; r < RR + 4; ++r) {
        float4 cur = p0;
        p0 = p1; p1 = p2; p2 = p3;
        if (r < RR) p3 = LOADROW(r0 + 2 + r);   // statically elided for r>=RR

        // halo from neighbor lanes
        float L1 = __shfl_up(cur.w, 1);    // col c0-1
        float L2 = __shfl_up(cur.z, 1);    // col c0-2
        float R1 = __shfl_down(cur.x, 1);  // col c0+4
        float R2 = __shfl_down(cur.y, 1);  // col c0+5
        if (lane == 0)  { L1 = NINF; L2 = NINF; }
        if (lane == 63) { R1 = NINF; R2 = NINF; }

        // horizontal 5-window maxes for the 4 owned columns
        float myz   = fmaxf(cur.y, cur.z);
        float mxyz  = fmaxf(cur.x, myz);
        float myzw  = fmaxf(myz, cur.w);
        float mxyzw = fmaxf(mxyz, cur.w);
        float hm0 = fmaxf(fmaxf(L2, L1), mxyz);          // cols c-2..c+2 for j=0
        float hm1 = fmaxf(L1, mxyzw);                    // j=1
        float hm2 = fmaxf(mxyzw, R1);                    // j=2
        float hm3 = fmaxf(myzw, fmaxf(R1, R2));          // j=3

        // shift vertical chains (renamed away by full unroll)
        #pragma unroll
        for (int k = 0; k < 4; ++k) {
            h[k][0] = h[k + 1][0]; h[k][1] = h[k + 1][1];
            h[k][2] = h[k + 1][2]; h[k][3] = h[k + 1][3];
        }
        h[4][0] = hm0; h[4][1] = hm1; h[4][2] = hm2; h[4][3] = hm3;
        #pragma unroll
        for (int j = 0; j < 4; ++j) { raw0[j] = raw1[j]; raw1[j] = raw2[j]; }
        raw2[0] = cur.x; raw2[1] = cur.y; raw2[2] = cur.z; raw2[3] = cur.w;

        if (r >= 4) {
            const int rout = r0 + r - 4;
            #pragma unroll
            for (int j = 0; j < 4; ++j) {
                float wmax = fmaxf(fmaxf(fmaxf(h[0][j], h[1][j]),
                                         fmaxf(h[2][j], h[3][j])), h[4][j]);
                float rv = raw0[j];
                // peak test (exact equality, same arithmetic as reference).
                // strict > keeps earliest (smallest-index) equal value ranked
                // first within this thread; non-peaks never inserted.
                if (rv == wmax && rv > v2) {
                    int idx = rout * W + lane * 4 + j;
                    if (rv > v1) {
                        v2 = v1; i2 = i1;
                        if (rv > v0) { v1 = v0; i1 = i0; v0 = rv; i0 = idx; }
                        else         { v1 = rv; i1 = idx; }
                    } else { v2 = rv; i2 = idx; }
                }
            }
        }
    }

    // wave butterfly reduction of per-thread top-3 (full tie-break comparator)
    #pragma unroll
    for (int m = 1; m < 64; m <<= 1) {
        float a0 = __shfl_xor(v0, m), a1 = __shfl_xor(v1, m), a2 = __shfl_xor(v2, m);
        int   c0 = __shfl_xor(i0, m), c1 = __shfl_xor(i1, m), c2 = __shfl_xor(i2, m);
        merge3(a0, c0, v0, i0, v1, i1, v2, i2);
        merge3(a1, c1, v0, i0, v1, i1, v2, i2);
        merge3(a2, c2, v0, i0, v1, i1, v2, i2);
    }

    if (lane == 0) {
        Cand* o = ws + (size_t)g * 3;
        o[0].v = v0; o[0].i = i0;
        o[1].v = v1; o[1].i = i1;
        o[2].v = v2; o[2].i = i2;
    }
}

__global__ __launch_bounds__(256) void peaks_phase2(const Cand* __restrict__ ws,
                                                    float* __restrict__ out) {
    const int b = blockIdx.x;
    const int t = threadIdx.x;
    const float NINF = -__builtin_inff();

    float v0 = NINF, v1 = NINF, v2 = NINF;
    int   i0 = 0x7fffffff, i1 = 0x7fffffff, i2 = 0x7fffffff;
    if (t < NC) {
        Cand e = ws[(size_t)b * NC + t];
        v0 = e.v; i0 = e.i;
    }

    __shared__ float rv[256][3];
    __shared__ int   ri[256][3];
    rv[t][0] = v0; rv[t][1] = v1; rv[t][2] = v2;
    ri[t][0] = i0; ri[t][1] = i1; ri[t][2] = i2;
    __syncthreads();
    for (int s = 128; s > 0; s >>= 1) {
        if (t < s) {
            merge3(rv[t + s][0], ri[t + s][0], v0, i0, v1, i1, v2, i2);
            merge3(rv[t + s][1], ri[t + s][1], v0, i0, v1, i1, v2, i2);
            merge3(rv[t + s][2], ri[t + s][2], v0, i0, v1, i1, v2, i2);
            rv[t][0] = v0; rv[t][1] = v1; rv[t][2] = v2;
            ri[t][0] = i0; ri[t][1] = i1; ri[t][2] = i2;
        }
        __syncthreads();
    }

    if (t == 0) {
        // positions [64,3,3] at 0 ; scores [64,3] at 576 ; mask [64,3] at 768
        float* pos = out + (size_t)b * 9;
        float* sco = out + 576 + (size_t)b * 3;
        float* msk = out + 768 + (size_t)b * 3;

        pos[0] = (float)(i0 >> 16);
        pos[1] = (float)((i0 >> 8) & 255);
        pos[2] = (float)(i0 & 255);
        sco[0] = v0;
        msk[0] = (v0 > -1e30f) ? 1.0f : 0.0f;

        pos[3] = (float)(i1 >> 16);
        pos[4] = (float)((i1 >> 8) & 255);
        pos[5] = (float)(i1 & 255);
        sco[1] = v1;
        msk[1] = (v1 > -1e30f) ? 1.0f : 0.0f;

        pos[6] = (float)(i2 >> 16);
        pos[7] = (float)((i2 >> 8) & 255);
        pos[8] = (float)(i2 & 255);
        sco[2] = v2;
        msk[2] = (v2 > -1e30f) ? 1.0f : 0.0f;
    }
}

extern "C" void kernel_launch(void* const* d_in, const int* in_sizes, int n_in,
                              void* d_out, int out_size, void* d_ws, size_t ws_size,
                              hipStream_t stream) {
    const float* hm = (const float*)d_in[0];
    float* out = (float*)d_out;
    Cand* ws = (Cand*)d_ws;  // 64*80*3*8 = 122880 bytes

    peaks_phase1<<<(BS * SPB) / WPB, 64 * WPB, 0, stream>>>(hm, ws);
    peaks_phase2<<<BS, 256, 0, stream>>>(ws, out);
}